// Round 1
// baseline (1075.003 us; speedup 1.0000x reference)
//
#include <hip/hip_runtime.h>
#include <math.h>

#define S_LEN 1024
#define D_MOD 512
#define NH 8
#define DK 64
#define NB 8

// ---------------------------------------------------------------------------
// Generic 512-K GEMM: C = A[M,512] @ W[512,512] + bias (+ residual R)
// tile 128x128, 256 threads, 8x8 accum per thread, BK=16.
// head_layout=1: scatter output to [B, H, S, 64]; else plain [M, 512].
// ---------------------------------------------------------------------------
__global__ __launch_bounds__(256) void gemm512_kern(
    const float* __restrict__ A, const float* __restrict__ W,
    const float* __restrict__ bias, const float* __restrict__ R,
    float* __restrict__ C, int head_layout)
{
  __shared__ float Ast[16][132];  // A tile transposed: [k][m], +4 pad
  __shared__ float Ws[16][132];   // W tile: [k][n], +4 pad

  const int t = threadIdx.x;
  const int m0 = blockIdx.y * 128;
  const int n0 = blockIdx.x * 128;
  const int tr = t >> 4;         // 0..15
  const int tc = t & 15;         // 0..15
  const int mr = tr * 8;
  const int nc = tc * 8;

  float acc[8][8];
#pragma unroll
  for (int i = 0; i < 8; ++i)
#pragma unroll
    for (int j = 0; j < 8; ++j) acc[i][j] = 0.f;

  const int li = t >> 2;         // 0..63
  const int lk = (t & 3) * 4;    // 0,4,8,12
  const int wk = t >> 4;         // 0..15
  const int wn = (t & 15) * 8;   // 0..120

  for (int k0 = 0; k0 < 512; k0 += 16) {
    float4 a0 = *(const float4*)&A[(size_t)(m0 + li) * 512 + k0 + lk];
    float4 a1 = *(const float4*)&A[(size_t)(m0 + 64 + li) * 512 + k0 + lk];
    float4 w0 = *(const float4*)&W[(size_t)(k0 + wk) * 512 + n0 + wn];
    float4 w1 = *(const float4*)&W[(size_t)(k0 + wk) * 512 + n0 + wn + 4];
    __syncthreads();  // protect LDS from previous iteration's readers
    Ast[lk + 0][li] = a0.x; Ast[lk + 1][li] = a0.y;
    Ast[lk + 2][li] = a0.z; Ast[lk + 3][li] = a0.w;
    Ast[lk + 0][64 + li] = a1.x; Ast[lk + 1][64 + li] = a1.y;
    Ast[lk + 2][64 + li] = a1.z; Ast[lk + 3][64 + li] = a1.w;
    *(float4*)&Ws[wk][wn] = w0;
    *(float4*)&Ws[wk][wn + 4] = w1;
    __syncthreads();
#pragma unroll
    for (int k = 0; k < 16; ++k) {
      float4 aA = *(const float4*)&Ast[k][mr];
      float4 aB = *(const float4*)&Ast[k][mr + 4];
      float4 wA = *(const float4*)&Ws[k][nc];
      float4 wB = *(const float4*)&Ws[k][nc + 4];
      float av[8] = {aA.x, aA.y, aA.z, aA.w, aB.x, aB.y, aB.z, aB.w};
      float wv[8] = {wA.x, wA.y, wA.z, wA.w, wB.x, wB.y, wB.z, wB.w};
#pragma unroll
      for (int i = 0; i < 8; ++i)
#pragma unroll
        for (int j = 0; j < 8; ++j) acc[i][j] += av[i] * wv[j];
    }
  }

  float bv_[8];
#pragma unroll
  for (int j = 0; j < 8; ++j) bv_[j] = bias[n0 + nc + j];

#pragma unroll
  for (int i = 0; i < 8; ++i) {
    const int m = m0 + mr + i;
    float vout[8];
#pragma unroll
    for (int j = 0; j < 8; ++j) vout[j] = acc[i][j] + bv_[j];
    if (R) {
      const float* rp = &R[(size_t)m * 512 + n0 + nc];
      float4 r0 = *(const float4*)rp;
      float4 r1 = *(const float4*)(rp + 4);
      vout[0] += r0.x; vout[1] += r0.y; vout[2] += r0.z; vout[3] += r0.w;
      vout[4] += r1.x; vout[5] += r1.y; vout[6] += r1.z; vout[7] += r1.w;
    }
    float* dst;
    if (head_layout) {
      const int b = m >> 10;
      const int s = m & 1023;
      const int n = n0 + nc;               // multiple of 8; stays in one head
      const int h = n >> 6;
      const int jj = n & 63;
      dst = &C[(((size_t)b * NH + h) * S_LEN + s) * DK + jj];
    } else {
      dst = &C[(size_t)m * 512 + n0 + nc];
    }
    *(float4*)dst = make_float4(vout[0], vout[1], vout[2], vout[3]);
    *(float4*)(dst + 4) = make_float4(vout[4], vout[5], vout[6], vout[7]);
  }
}

// ---------------------------------------------------------------------------
// Fused dual-score causal attention, online softmax.
// Block = 256 thr, one (b, h, 32-row q-tile); K-tiles of 64.
// Scores: proj QK^T/8 + (mask ? raw QK^T/sqrt(512)*te : 0), strict causal.
// ---------------------------------------------------------------------------
__global__ __launch_bounds__(256) void attn_kern(
    const float* __restrict__ Qh, const float* __restrict__ Kh,
    const float* __restrict__ Vh, const float* __restrict__ q_in,
    const float* __restrict__ k_in, const int* __restrict__ smask,
    const float* __restrict__ gammas, float* __restrict__ O)
{
  __shared__ float qs[32][68];   // projected Q tile [q][j]
  __shared__ float qr[32][68];   // raw q tile      [q][j]
  __shared__ float ksT[64][68];  // projected K tile transposed [j][k]
  __shared__ float krT[64][68];  // raw k tile transposed       [j][k]
  __shared__ float vs[64][68];   // V tile [k][c]
  __shared__ float ps[32][68];   // probs tile [q][k]

  const int t = threadIdx.x;
  const int bh = blockIdx.y;
  const int b = bh >> 3;
  const int h = bh & 7;
  const int q0 = blockIdx.x * 32;

  // ---- load Q tiles (proj + raw) ----
  {
    const int i = t >> 3;           // 0..31
    const int j0 = (t & 7) * 8;     // 0..56
    const float* qp = &Qh[(((size_t)b * NH + h) * S_LEN + q0 + i) * DK + j0];
    *(float4*)&qs[i][j0] = *(const float4*)qp;
    *(float4*)&qs[i][j0 + 4] = *(const float4*)(qp + 4);
    const float* rp = &q_in[((size_t)b * S_LEN + q0 + i) * D_MOD + h * DK + j0];
    *(float4*)&qr[i][j0] = *(const float4*)rp;
    *(float4*)&qr[i][j0 + 4] = *(const float4*)(rp + 4);
  }

  const int r = t >> 3;            // my q-row within tile (0..31)
  const int kk = (t & 7) * 8;      // my 8-key / 8-col offset
  const int qg = q0 + r;           // global q index

  const float gam = gammas[h];
  float te = expf(-log1pf(expf(gam)));   // exp(-softplus(gamma))
  te = fminf(fmaxf(te, 1e-5f), 1e5f);
  const float sscale = te * 0.044194173824159216f;  // te / sqrt(512)

  float m_run = -1e30f;
  float l_run = 0.f;
  float o_acc[8];
#pragma unroll
  for (int u = 0; u < 8; ++u) o_acc[u] = 0.f;

  const int qmax = q0 + 31;        // strict causal: keys valid iff k < qg
  for (int k0 = 0; k0 < qmax; k0 += 64) {
    __syncthreads();  // previous PV readers done; also orders Q-tile writes
    // ---- load K (proj+raw, transposed) and V tiles ----
    {
      const int j0 = (t & 7) * 8;
      const int kc0 = t >> 3;      // 0..31
#pragma unroll
      for (int half = 0; half < 2; ++half) {
        const int kc = kc0 + half * 32;
        const float* kp = &Kh[(((size_t)b * NH + h) * S_LEN + k0 + kc) * DK + j0];
        float4 kA = *(const float4*)kp;
        float4 kB = *(const float4*)(kp + 4);
        const float* rp = &k_in[((size_t)b * S_LEN + k0 + kc) * D_MOD + h * DK + j0];
        float4 rA = *(const float4*)rp;
        float4 rB = *(const float4*)(rp + 4);
        const float* vp = &Vh[(((size_t)b * NH + h) * S_LEN + k0 + kc) * DK + j0];
        float4 vA = *(const float4*)vp;
        float4 vB = *(const float4*)(vp + 4);
        ksT[j0 + 0][kc] = kA.x; ksT[j0 + 1][kc] = kA.y;
        ksT[j0 + 2][kc] = kA.z; ksT[j0 + 3][kc] = kA.w;
        ksT[j0 + 4][kc] = kB.x; ksT[j0 + 5][kc] = kB.y;
        ksT[j0 + 6][kc] = kB.z; ksT[j0 + 7][kc] = kB.w;
        krT[j0 + 0][kc] = rA.x; krT[j0 + 1][kc] = rA.y;
        krT[j0 + 2][kc] = rA.z; krT[j0 + 3][kc] = rA.w;
        krT[j0 + 4][kc] = rB.x; krT[j0 + 5][kc] = rB.y;
        krT[j0 + 6][kc] = rB.z; krT[j0 + 7][kc] = rB.w;
        *(float4*)&vs[kc][j0] = vA;
        *(float4*)&vs[kc][j0 + 4] = vB;
      }
    }
    // ---- state_mask for my 8 keys (coalesced int4 x2) ----
    const int* mp = &smask[((size_t)b * S_LEN + qg) * S_LEN + k0 + kk];
    const int4 mA = *(const int4*)mp;
    const int4 mB = *(const int4*)(mp + 4);
    __syncthreads();

    // ---- scores: both matrices, dot over j=0..63 ----
    float sc[8], sr[8];
#pragma unroll
    for (int u = 0; u < 8; ++u) { sc[u] = 0.f; sr[u] = 0.f; }
#pragma unroll 4
    for (int j = 0; j < 64; ++j) {
      const float a = qs[r][j];
      const float ar = qr[r][j];
      const float4 kA = *(const float4*)&ksT[j][kk];
      const float4 kB = *(const float4*)&ksT[j][kk + 4];
      const float4 rA = *(const float4*)&krT[j][kk];
      const float4 rB = *(const float4*)&krT[j][kk + 4];
      sc[0] += a * kA.x; sc[1] += a * kA.y; sc[2] += a * kA.z; sc[3] += a * kA.w;
      sc[4] += a * kB.x; sc[5] += a * kB.y; sc[6] += a * kB.z; sc[7] += a * kB.w;
      sr[0] += ar * rA.x; sr[1] += ar * rA.y; sr[2] += ar * rA.z; sr[3] += ar * rA.w;
      sr[4] += ar * rB.x; sr[5] += ar * rB.y; sr[6] += ar * rB.z; sr[7] += ar * rB.w;
    }

    const int mv[8] = {mA.x, mA.y, mA.z, mA.w, mB.x, mB.y, mB.z, mB.w};
    float s[8];
    float tmax = -1e30f;
#pragma unroll
    for (int u = 0; u < 8; ++u) {
      const int kg = k0 + kk + u;
      float v = sc[u] * 0.125f;                 // / sqrt(dk)
      if (mv[u] != 0) v += sr[u] * sscale;      // s_scores only where mask
      s[u] = (kg < qg) ? v : -1e30f;            // strict causal
      tmax = fmaxf(tmax, s[u]);
    }
    // reduce max across the 8 lanes of this row (consecutive lanes)
#pragma unroll
    for (int off = 1; off < 8; off <<= 1)
      tmax = fmaxf(tmax, __shfl_xor(tmax, off, 64));
    const float newm = fmaxf(m_run, tmax);
    const float alpha = __expf(m_run - newm);   // 0 on first real tile; 1 if empty
    float rowsum = 0.f;
#pragma unroll
    for (int u = 0; u < 8; ++u) {
      const float p = (s[u] > -1e29f) ? __expf(s[u] - newm) : 0.f;
      ps[r][kk + u] = p;
      rowsum += p;
    }
#pragma unroll
    for (int off = 1; off < 8; off <<= 1)
      rowsum += __shfl_xor(rowsum, off, 64);
    l_run = l_run * alpha + rowsum;
    m_run = newm;
#pragma unroll
    for (int u = 0; u < 8; ++u) o_acc[u] *= alpha;
    __syncthreads();  // ps visible before PV

    // ---- PV accumulate: o[c] += sum_k p[k] * V[k][c] ----
#pragma unroll 8
    for (int k = 0; k < 64; ++k) {
      const float pk = ps[r][k];
      const float4 vA = *(const float4*)&vs[k][kk];
      const float4 vB = *(const float4*)&vs[k][kk + 4];
      o_acc[0] += pk * vA.x; o_acc[1] += pk * vA.y;
      o_acc[2] += pk * vA.z; o_acc[3] += pk * vA.w;
      o_acc[4] += pk * vB.x; o_acc[5] += pk * vB.y;
      o_acc[6] += pk * vB.z; o_acc[7] += pk * vB.w;
    }
  }

  const float inv = (l_run > 0.f) ? 1.f / l_run : 0.f;  // row 0: no keys -> 0
  float* op = &O[((size_t)b * S_LEN + qg) * D_MOD + h * DK + kk];
  *(float4*)op = make_float4(o_acc[0] * inv, o_acc[1] * inv,
                             o_acc[2] * inv, o_acc[3] * inv);
  *(float4*)(op + 4) = make_float4(o_acc[4] * inv, o_acc[5] * inv,
                                   o_acc[6] * inv, o_acc[7] * inv);
}

// ---------------------------------------------------------------------------
// LayerNorm over D=512, one wave per row.
// ---------------------------------------------------------------------------
__global__ __launch_bounds__(256) void ln_kern(
    const float* __restrict__ X, const float* __restrict__ gw,
    const float* __restrict__ bw, float* __restrict__ out)
{
  const int row = blockIdx.x * 4 + (threadIdx.x >> 6);
  const int lane = threadIdx.x & 63;
  const int c = lane * 8;
  const float* xp = &X[(size_t)row * D_MOD + c];
  const float4 x0 = *(const float4*)xp;
  const float4 x1 = *(const float4*)(xp + 4);
  float xv[8] = {x0.x, x0.y, x0.z, x0.w, x1.x, x1.y, x1.z, x1.w};
  float sum = 0.f;
#pragma unroll
  for (int u = 0; u < 8; ++u) sum += xv[u];
#pragma unroll
  for (int off = 1; off < 64; off <<= 1) sum += __shfl_xor(sum, off, 64);
  const float mu = sum * (1.f / 512.f);
  float ss = 0.f;
#pragma unroll
  for (int u = 0; u < 8; ++u) { xv[u] -= mu; ss += xv[u] * xv[u]; }
#pragma unroll
  for (int off = 1; off < 64; off <<= 1) ss += __shfl_xor(ss, off, 64);
  const float rstd = rsqrtf(ss * (1.f / 512.f) + 1e-5f);
  const float4 g0 = *(const float4*)&gw[c];
  const float4 g1 = *(const float4*)&gw[c + 4];
  const float4 b0 = *(const float4*)&bw[c];
  const float4 b1 = *(const float4*)&bw[c + 4];
  float* op = &out[(size_t)row * D_MOD + c];
  *(float4*)op = make_float4(xv[0] * rstd * g0.x + b0.x,
                             xv[1] * rstd * g0.y + b0.y,
                             xv[2] * rstd * g0.z + b0.z,
                             xv[3] * rstd * g0.w + b0.w);
  *(float4*)(op + 4) = make_float4(xv[4] * rstd * g1.x + b1.x,
                                   xv[5] * rstd * g1.y + b1.y,
                                   xv[6] * rstd * g1.z + b1.z,
                                   xv[7] * rstd * g1.w + b1.w);
}

// ---------------------------------------------------------------------------
extern "C" void kernel_launch(void* const* d_in, const int* in_sizes, int n_in,
                              void* d_out, int out_size, void* d_ws, size_t ws_size,
                              hipStream_t stream)
{
  const float* q_in  = (const float*)d_in[0];
  const float* k_in  = (const float*)d_in[1];
  const float* v_in  = (const float*)d_in[2];
  const int*   smask = (const int*)d_in[3];
  const float* Wq = (const float*)d_in[4];
  const float* bq = (const float*)d_in[5];
  const float* Wv = (const float*)d_in[6];
  const float* bv = (const float*)d_in[7];
  const float* Wo = (const float*)d_in[8];
  const float* bo = (const float*)d_in[9];
  const float* gammas = (const float*)d_in[10];
  const float* ln_g = (const float*)d_in[11];
  const float* ln_b = (const float*)d_in[12];
  float* out = (float*)d_out;

  const size_t NTOK = (size_t)NB * S_LEN * D_MOD;  // 4,194,304 floats
  float* Qh = (float*)d_ws;
  float* Kh = Qh + NTOK;
  float* Vh = Kh + NTOK;
  float* O  = Vh + NTOK;
  float* X  = Qh;  // reuse Qh region after attention

  const dim3 tb(256);
  const dim3 gg(4, 64);     // 128x128 tiles over [8192, 512]
  gemm512_kern<<<gg, tb, 0, stream>>>(q_in, Wq, bq, nullptr, Qh, 1);
  gemm512_kern<<<gg, tb, 0, stream>>>(k_in, Wq, bq, nullptr, Kh, 1);
  gemm512_kern<<<gg, tb, 0, stream>>>(v_in, Wv, bv, nullptr, Vh, 1);
  attn_kern<<<dim3(32, 64), tb, 0, stream>>>(Qh, Kh, Vh, q_in, k_in, smask,
                                             gammas, O);
  gemm512_kern<<<gg, tb, 0, stream>>>(O, Wo, bo, q_in, X, 0);
  ln_kern<<<2048, tb, 0, stream>>>(X, ln_g, ln_b, out);
}

// Round 2
// 657.665 us; speedup vs baseline: 1.6346x; 1.6346x over previous
//
#include <hip/hip_runtime.h>
#include <math.h>

#define S_LEN 1024
#define D_MOD 512
#define NH 8
#define DK 64
#define NB 8

typedef __attribute__((ext_vector_type(8))) short short8;   // 8 bf16 in 4 VGPRs
typedef __attribute__((ext_vector_type(4))) float floatx4;  // MFMA accumulator

union U8 { ushort u[8]; short8 v; };

__device__ __forceinline__ ushort f2bf(float x) {
  unsigned u = __float_as_uint(x);
  unsigned r = (u + 0x7fffu + ((u >> 16) & 1u)) >> 16;  // RNE
  return (ushort)r;
}

// ---------------------------------------------------------------------------
// fp32 -> bf16 convert (vectorized by 8)
// ---------------------------------------------------------------------------
__global__ __launch_bounds__(256) void cvt_bf16_kern(
    const float* __restrict__ src, ushort* __restrict__ dst, int n8)
{
  int i = blockIdx.x * 256 + threadIdx.x;
  if (i >= n8) return;
  const float4 a = *((const float4*)src + i * 2);
  const float4 b = *((const float4*)src + i * 2 + 1);
  U8 o;
  o.u[0] = f2bf(a.x); o.u[1] = f2bf(a.y); o.u[2] = f2bf(a.z); o.u[3] = f2bf(a.w);
  o.u[4] = f2bf(b.x); o.u[5] = f2bf(b.y); o.u[6] = f2bf(b.z); o.u[7] = f2bf(b.w);
  *(short8*)(dst + (size_t)i * 8) = o.v;
}

// ---------------------------------------------------------------------------
// Generic 512-K GEMM: tile 128x128, 256 threads, 8x8 accum per thread, BK=16.
// out_mode 0: fp32 [M,512] (+bias, +residual R)
// out_mode 1: bf16 head layout [B, H, S, 64] (+bias)
// ---------------------------------------------------------------------------
__global__ __launch_bounds__(256) void gemm512_kern(
    const float* __restrict__ A, const float* __restrict__ W,
    const float* __restrict__ bias, const float* __restrict__ R,
    void* __restrict__ Cout, int out_mode)
{
  __shared__ float Ast[16][132];
  __shared__ float Ws[16][132];

  const int t = threadIdx.x;
  const int m0 = blockIdx.y * 128;
  const int n0 = blockIdx.x * 128;
  const int mr = (t >> 4) * 8;
  const int nc = (t & 15) * 8;

  float acc[8][8];
#pragma unroll
  for (int i = 0; i < 8; ++i)
#pragma unroll
    for (int j = 0; j < 8; ++j) acc[i][j] = 0.f;

  const int li = t >> 2;
  const int lk = (t & 3) * 4;
  const int wk = t >> 4;
  const int wn = (t & 15) * 8;

  for (int k0 = 0; k0 < 512; k0 += 16) {
    float4 a0 = *(const float4*)&A[(size_t)(m0 + li) * 512 + k0 + lk];
    float4 a1 = *(const float4*)&A[(size_t)(m0 + 64 + li) * 512 + k0 + lk];
    float4 w0 = *(const float4*)&W[(size_t)(k0 + wk) * 512 + n0 + wn];
    float4 w1 = *(const float4*)&W[(size_t)(k0 + wk) * 512 + n0 + wn + 4];
    __syncthreads();
    Ast[lk + 0][li] = a0.x; Ast[lk + 1][li] = a0.y;
    Ast[lk + 2][li] = a0.z; Ast[lk + 3][li] = a0.w;
    Ast[lk + 0][64 + li] = a1.x; Ast[lk + 1][64 + li] = a1.y;
    Ast[lk + 2][64 + li] = a1.z; Ast[lk + 3][64 + li] = a1.w;
    *(float4*)&Ws[wk][wn] = w0;
    *(float4*)&Ws[wk][wn + 4] = w1;
    __syncthreads();
#pragma unroll
    for (int k = 0; k < 16; ++k) {
      float4 aA = *(const float4*)&Ast[k][mr];
      float4 aB = *(const float4*)&Ast[k][mr + 4];
      float4 wA = *(const float4*)&Ws[k][nc];
      float4 wB = *(const float4*)&Ws[k][nc + 4];
      float av[8] = {aA.x, aA.y, aA.z, aA.w, aB.x, aB.y, aB.z, aB.w};
      float wv[8] = {wA.x, wA.y, wA.z, wA.w, wB.x, wB.y, wB.z, wB.w};
#pragma unroll
      for (int i = 0; i < 8; ++i)
#pragma unroll
        for (int j = 0; j < 8; ++j) acc[i][j] += av[i] * wv[j];
    }
  }

  float bv_[8];
#pragma unroll
  for (int j = 0; j < 8; ++j) bv_[j] = bias[n0 + nc + j];

#pragma unroll
  for (int i = 0; i < 8; ++i) {
    const int m = m0 + mr + i;
    float vout[8];
#pragma unroll
    for (int j = 0; j < 8; ++j) vout[j] = acc[i][j] + bv_[j];
    if (out_mode == 0) {
      if (R) {
        const float* rp = &R[(size_t)m * 512 + n0 + nc];
        float4 r0 = *(const float4*)rp;
        float4 r1 = *(const float4*)(rp + 4);
        vout[0] += r0.x; vout[1] += r0.y; vout[2] += r0.z; vout[3] += r0.w;
        vout[4] += r1.x; vout[5] += r1.y; vout[6] += r1.z; vout[7] += r1.w;
      }
      float* dst = &((float*)Cout)[(size_t)m * 512 + n0 + nc];
      *(float4*)dst = make_float4(vout[0], vout[1], vout[2], vout[3]);
      *(float4*)(dst + 4) = make_float4(vout[4], vout[5], vout[6], vout[7]);
    } else {
      // bf16 head layout [B,H,S,64]
      const int b = m >> 10;
      const int s = m & 1023;
      const int n = n0 + nc;
      const int h = n >> 6;
      const int jj = n & 63;
      U8 o;
#pragma unroll
      for (int j = 0; j < 8; ++j) o.u[j] = f2bf(vout[j]);
      ushort* dst = &((ushort*)Cout)[(((size_t)b * NH + h) * S_LEN + s) * DK + jj];
      *(short8*)dst = o.v;
    }
  }
}

// ---------------------------------------------------------------------------
// Transpose V head-layout [B,H,S,64] bf16 -> Vt [B,H,64,S] bf16
// ---------------------------------------------------------------------------
__global__ __launch_bounds__(256) void vtrans_kern(
    const ushort* __restrict__ V, ushort* __restrict__ Vt)
{
  __shared__ __align__(16) ushort tile[64][72];
  const int t = threadIdx.x;
  const int bh = blockIdx.y;
  const int s0 = blockIdx.x * 64;
  {
    const int r = t >> 2, c0 = (t & 3) * 16;
    const ushort* p = V + ((size_t)bh * S_LEN + s0 + r) * DK + c0;
    *(short8*)&tile[r][c0] = *(const short8*)p;
    *(short8*)&tile[r][c0 + 8] = *(const short8*)(p + 8);
  }
  __syncthreads();
  {
    const int c = t >> 2, sg = (t & 3) * 16;
    U8 lo, hi;
#pragma unroll
    for (int j = 0; j < 8; ++j) lo.u[j] = tile[sg + j][c];
#pragma unroll
    for (int j = 0; j < 8; ++j) hi.u[j] = tile[sg + 8 + j][c];
    ushort* q = Vt + ((size_t)bh * DK + c) * S_LEN + s0 + sg;
    *(short8*)q = lo.v;
    *(short8*)(q + 8) = hi.v;
  }
}

// ---------------------------------------------------------------------------
// MFMA fused dual-score causal attention, online softmax.
// Block = 256 thr (4 waves) = one (b,h, 64-q block); wave owns 16 q rows.
// Wave-local causal trip count; no block barriers. P round-trips per-wave LDS.
// Frag pattern (HW-verified gemm_bt): arg0 = A rows (lane&15 = m, k=quad*8+j),
// arg1 = B^T rows (lane&15 = n), D: col=lane&15, row=quad*4+reg.
// ---------------------------------------------------------------------------
__global__ __launch_bounds__(256) void attn_mfma_kern(
    const ushort* __restrict__ Qh, const ushort* __restrict__ Kh,
    const ushort* __restrict__ Vt, const ushort* __restrict__ qraw,
    const ushort* __restrict__ kraw, const int* __restrict__ smask,
    const float* __restrict__ gammas, float* __restrict__ O)
{
  __shared__ __align__(16) ushort Plds[4][16][72];

  const int t = threadIdx.x;
  const int w = t >> 6;
  const int lane = t & 63;
  const int quad = lane >> 4;
  const int i16 = lane & 15;
  const int bh = blockIdx.y;
  const int b = bh >> 3;
  const int h = bh & 7;
  const int q0 = blockIdx.x * 64;
  const int qbase = q0 + w * 16;

  const float gam = gammas[h];
  float te = __expf(-log1pf(__expf(gam)));
  te = fminf(fmaxf(te, 1e-5f), 1e5f);
  const float sscale = te * 0.044194173824159216f;  // te / sqrt(512)

  // Q fragments (held for whole kernel)
  short8 Qp[2], Qr[2];
  {
    const ushort* qp = Qh + ((size_t)bh * S_LEN + qbase + i16) * DK + quad * 8;
    const ushort* qq = qraw + ((size_t)b * S_LEN + qbase + i16) * D_MOD + h * DK + quad * 8;
#pragma unroll
    for (int s = 0; s < 2; ++s) {
      Qp[s] = *(const short8*)(qp + s * 32);
      Qr[s] = *(const short8*)(qq + s * 32);
    }
  }

  floatx4 Oacc[4];
#pragma unroll
  for (int t4 = 0; t4 < 4; ++t4) Oacc[t4] = (floatx4)(0.f);
  float m_run[4] = {-1e30f, -1e30f, -1e30f, -1e30f};
  float l_run[4] = {0.f, 0.f, 0.f, 0.f};

  const int kend = qbase + 15;  // strict causal: need keys k < q <= qbase+15
  for (int k0 = 0; k0 < kend; k0 += 64) {
    // ---- mask loads (issue early) ----
    int mv[4][4];
    {
      const size_t mbase = ((size_t)b * S_LEN + qbase + quad * 4) * S_LEN + k0 + i16;
#pragma unroll
      for (int r = 0; r < 4; ++r)
#pragma unroll
        for (int t4 = 0; t4 < 4; ++t4)
          mv[t4][r] = smask[mbase + (size_t)r * S_LEN + t4 * 16];
    }

    // ---- scores: 16 MFMAs ----
    floatx4 accp[4], accr[4];
#pragma unroll
    for (int t4 = 0; t4 < 4; ++t4) { accp[t4] = (floatx4)(0.f); accr[t4] = (floatx4)(0.f); }
#pragma unroll
    for (int s = 0; s < 2; ++s) {
      const ushort* kp_base = Kh + ((size_t)bh * S_LEN + k0 + i16) * DK + s * 32 + quad * 8;
      const ushort* kr_base = kraw + ((size_t)b * S_LEN + k0 + i16) * D_MOD + h * DK + s * 32 + quad * 8;
      short8 kp[4], kr8[4];
#pragma unroll
      for (int t4 = 0; t4 < 4; ++t4) kp[t4] = *(const short8*)(kp_base + (size_t)t4 * 16 * DK);
#pragma unroll
      for (int t4 = 0; t4 < 4; ++t4) kr8[t4] = *(const short8*)(kr_base + (size_t)t4 * 16 * D_MOD);
#pragma unroll
      for (int t4 = 0; t4 < 4; ++t4)
        accp[t4] = __builtin_amdgcn_mfma_f32_16x16x32_bf16(Qp[s], kp[t4], accp[t4], 0, 0, 0);
#pragma unroll
      for (int t4 = 0; t4 < 4; ++t4)
        accr[t4] = __builtin_amdgcn_mfma_f32_16x16x32_bf16(Qr[s], kr8[t4], accr[t4], 0, 0, 0);
    }

    // ---- dual-score combine + online softmax (rows = quad*4+r) ----
    float p[4][4];
#pragma unroll
    for (int r = 0; r < 4; ++r) {
      const int qg = qbase + quad * 4 + r;
      float sv[4];
      float mx = -1e30f;
#pragma unroll
      for (int t4 = 0; t4 < 4; ++t4) {
        const int kg = k0 + t4 * 16 + i16;
        float v = accp[t4][r] * 0.125f;
        if (mv[t4][r] != 0) v += accr[t4][r] * sscale;
        sv[t4] = (kg < qg) ? v : -1e30f;
        mx = fmaxf(mx, sv[t4]);
      }
#pragma unroll
      for (int off = 1; off < 16; off <<= 1) mx = fmaxf(mx, __shfl_xor(mx, off));
      const float newm = fmaxf(m_run[r], mx);
      const float alpha = __expf(m_run[r] - newm);
      m_run[r] = newm;
      float rs = 0.f;
#pragma unroll
      for (int t4 = 0; t4 < 4; ++t4) {
        const float pv = (sv[t4] > -1e29f) ? __expf(sv[t4] - newm) : 0.f;
        p[t4][r] = pv;
        rs += pv;
      }
#pragma unroll
      for (int off = 1; off < 16; off <<= 1) rs += __shfl_xor(rs, off);
      l_run[r] = l_run[r] * alpha + rs;
#pragma unroll
      for (int t4 = 0; t4 < 4; ++t4) Oacc[t4][r] *= alpha;
    }

    // ---- P -> LDS (bf16, row-major [16 q][64 k], pack pairs across lanes) ----
#pragma unroll
    for (int r = 0; r < 4; ++r)
#pragma unroll
      for (int t4 = 0; t4 < 4; ++t4) {
        unsigned mine = f2bf(p[t4][r]);
        unsigned part = (unsigned)__shfl_xor((int)mine, 1);
        if ((i16 & 1) == 0) {
          unsigned word = mine | (part << 16);
          *(unsigned*)&Plds[w][quad * 4 + r][t4 * 16 + i16] = word;
        }
      }

    // ---- PV: 8 MFMAs. A = P rows from LDS, B^T = Vt rows from global ----
#pragma unroll
    for (int s = 0; s < 2; ++s) {
      short8 a = *(const short8*)&Plds[w][i16][s * 32 + quad * 8];
      const ushort* vb = Vt + ((size_t)bh * DK + i16) * S_LEN + k0 + s * 32 + quad * 8;
#pragma unroll
      for (int t4 = 0; t4 < 4; ++t4) {
        short8 bf = *(const short8*)(vb + (size_t)t4 * 16 * S_LEN);
        Oacc[t4] = __builtin_amdgcn_mfma_f32_16x16x32_bf16(a, bf, Oacc[t4], 0, 0, 0);
      }
    }
  }

  // ---- epilogue: normalize, write O fp32 [B,S,512] ----
  float invl[4];
#pragma unroll
  for (int r = 0; r < 4; ++r) invl[r] = (l_run[r] > 0.f) ? 1.f / l_run[r] : 0.f;
#pragma unroll
  for (int r = 0; r < 4; ++r) {
    float* orow = O + ((size_t)b * S_LEN + qbase + quad * 4 + r) * D_MOD + h * DK;
#pragma unroll
    for (int t4 = 0; t4 < 4; ++t4)
      orow[t4 * 16 + i16] = Oacc[t4][r] * invl[r];
  }
}

// ---------------------------------------------------------------------------
// LayerNorm over D=512, one wave per row.
// ---------------------------------------------------------------------------
__global__ __launch_bounds__(256) void ln_kern(
    const float* __restrict__ X, const float* __restrict__ gw,
    const float* __restrict__ bw, float* __restrict__ out)
{
  const int row = blockIdx.x * 4 + (threadIdx.x >> 6);
  const int lane = threadIdx.x & 63;
  const int c = lane * 8;
  const float* xp = &X[(size_t)row * D_MOD + c];
  const float4 x0 = *(const float4*)xp;
  const float4 x1 = *(const float4*)(xp + 4);
  float xv[8] = {x0.x, x0.y, x0.z, x0.w, x1.x, x1.y, x1.z, x1.w};
  float sum = 0.f;
#pragma unroll
  for (int u = 0; u < 8; ++u) sum += xv[u];
#pragma unroll
  for (int off = 1; off < 64; off <<= 1) sum += __shfl_xor(sum, off, 64);
  const float mu = sum * (1.f / 512.f);
  float ss = 0.f;
#pragma unroll
  for (int u = 0; u < 8; ++u) { xv[u] -= mu; ss += xv[u] * xv[u]; }
#pragma unroll
  for (int off = 1; off < 64; off <<= 1) ss += __shfl_xor(ss, off, 64);
  const float rstd = rsqrtf(ss * (1.f / 512.f) + 1e-5f);
  const float4 g0 = *(const float4*)&gw[c];
  const float4 g1 = *(const float4*)&gw[c + 4];
  const float4 b0 = *(const float4*)&bw[c];
  const float4 b1 = *(const float4*)&bw[c + 4];
  float* op = &out[(size_t)row * D_MOD + c];
  *(float4*)op = make_float4(xv[0] * rstd * g0.x + b0.x,
                             xv[1] * rstd * g0.y + b0.y,
                             xv[2] * rstd * g0.z + b0.z,
                             xv[3] * rstd * g0.w + b0.w);
  *(float4*)(op + 4) = make_float4(xv[4] * rstd * g1.x + b1.x,
                                   xv[5] * rstd * g1.y + b1.y,
                                   xv[6] * rstd * g1.z + b1.z,
                                   xv[7] * rstd * g1.w + b1.w);
}

// ---------------------------------------------------------------------------
extern "C" void kernel_launch(void* const* d_in, const int* in_sizes, int n_in,
                              void* d_out, int out_size, void* d_ws, size_t ws_size,
                              hipStream_t stream)
{
  const float* q_in  = (const float*)d_in[0];
  const float* k_in  = (const float*)d_in[1];
  const float* v_in  = (const float*)d_in[2];
  const int*   smask = (const int*)d_in[3];
  const float* Wq = (const float*)d_in[4];
  const float* bq = (const float*)d_in[5];
  const float* Wv = (const float*)d_in[6];
  const float* bv = (const float*)d_in[7];
  const float* Wo = (const float*)d_in[8];
  const float* bo = (const float*)d_in[9];
  const float* gammas = (const float*)d_in[10];
  const float* ln_g = (const float*)d_in[11];
  const float* ln_b = (const float*)d_in[12];
  float* out = (float*)d_out;

  char* ws = (char*)d_ws;
  const size_t BF = (size_t)NB * S_LEN * D_MOD * sizeof(ushort);  // 8 MiB
  ushort* Qh = (ushort*)(ws);
  ushort* Kh = (ushort*)(ws + BF);
  ushort* qr = (ushort*)(ws + 2 * BF);
  ushort* kr = (ushort*)(ws + 3 * BF);
  ushort* Vt = (ushort*)(ws + 4 * BF);
  ushort* Vh = (ushort*)(ws + 5 * BF);          // temp (dead after vtrans)
  float*  O  = (float*)(ws + 5 * BF);           // overlaps Vh (Vh dead by attn)
  float*  X  = (float*)ws;                       // overlaps Qh..kr (dead by then)

  const dim3 tb(256);
  const int n8 = NB * S_LEN * D_MOD / 8;         // 524288

  cvt_bf16_kern<<<dim3(n8 / 256), tb, 0, stream>>>(q_in, qr, n8);
  cvt_bf16_kern<<<dim3(n8 / 256), tb, 0, stream>>>(k_in, kr, n8);

  const dim3 gg(4, 64);
  gemm512_kern<<<gg, tb, 0, stream>>>(q_in, Wq, bq, nullptr, Qh, 1);
  gemm512_kern<<<gg, tb, 0, stream>>>(k_in, Wq, bq, nullptr, Kh, 1);
  gemm512_kern<<<gg, tb, 0, stream>>>(v_in, Wv, bv, nullptr, Vh, 1);

  vtrans_kern<<<dim3(16, 64), tb, 0, stream>>>(Vh, Vt);

  attn_mfma_kern<<<dim3(16, 64), tb, 0, stream>>>(Qh, Kh, Vt, qr, kr, smask,
                                                  gammas, O);

  gemm512_kern<<<gg, tb, 0, stream>>>(O, Wo, bo, q_in, X, 0);
  ln_kern<<<2048, tb, 0, stream>>>(X, ln_g, ln_b, out);
}

// Round 3
// 375.711 us; speedup vs baseline: 2.8613x; 1.7505x over previous
//
#include <hip/hip_runtime.h>
#include <math.h>

#define S_LEN 1024
#define D_MOD 512
#define NH 8
#define DK 64
#define NB 8

typedef __attribute__((ext_vector_type(8))) short short8;   // 8 bf16 in 4 VGPRs
typedef __attribute__((ext_vector_type(4))) float floatx4;  // MFMA accumulator

union U8 { ushort u[8]; short8 v; };

__device__ __forceinline__ ushort f2bf(float x) {
  unsigned u = __float_as_uint(x);
  unsigned r = (u + 0x7fffu + ((u >> 16) & 1u)) >> 16;  // RNE
  return (ushort)r;
}

// ---------------------------------------------------------------------------
// fp32 -> bf16 convert (by 8)
// ---------------------------------------------------------------------------
__global__ __launch_bounds__(256) void cvt_bf16_kern(
    const float* __restrict__ src, ushort* __restrict__ dst, int n8)
{
  int i = blockIdx.x * 256 + threadIdx.x;
  if (i >= n8) return;
  const float4 a = *((const float4*)src + i * 2);
  const float4 b = *((const float4*)src + i * 2 + 1);
  U8 o;
  o.u[0] = f2bf(a.x); o.u[1] = f2bf(a.y); o.u[2] = f2bf(a.z); o.u[3] = f2bf(a.w);
  o.u[4] = f2bf(b.x); o.u[5] = f2bf(b.y); o.u[6] = f2bf(b.z); o.u[7] = f2bf(b.w);
  *(short8*)(dst + (size_t)i * 8) = o.v;
}

// ---------------------------------------------------------------------------
// Weight transpose+convert: W fp32 [512(k),512(n)] -> Wt bf16 [512(n),512(k)]
// ---------------------------------------------------------------------------
__global__ __launch_bounds__(256) void wtrans_kern(
    const float* __restrict__ W, ushort* __restrict__ Wt)
{
  __shared__ __align__(16) ushort tile[64][72];
  const int t = threadIdx.x;
  const int n0 = blockIdx.x * 64;
  const int k0 = blockIdx.y * 64;
  {
    const int r = t >> 2;            // k row 0..63
    const int c0 = (t & 3) * 16;     // n col
    const float* p = &W[(size_t)(k0 + r) * 512 + n0 + c0];
#pragma unroll
    for (int j = 0; j < 16; ++j) tile[r][c0 + j] = f2bf(p[j]);
  }
  __syncthreads();
  {
    const int c = t >> 2;            // n col 0..63
    const int kg = (t & 3) * 16;     // k chunk
    U8 lo, hi;
#pragma unroll
    for (int j = 0; j < 8; ++j) lo.u[j] = tile[kg + j][c];
#pragma unroll
    for (int j = 0; j < 8; ++j) hi.u[j] = tile[kg + 8 + j][c];
    ushort* q = &Wt[(size_t)(n0 + c) * 512 + k0 + kg];
    *(short8*)q = lo.v;
    *(short8*)(q + 8) = hi.v;
  }
}

// ---------------------------------------------------------------------------
// state_mask int32 [B,S,S] -> bit words u64 [B,S,S/64] (bit k = mask!=0)
// one wave per (b,q) row
// ---------------------------------------------------------------------------
__global__ __launch_bounds__(256) void maskbits_kern(
    const int* __restrict__ smask, unsigned long long* __restrict__ mb)
{
  const int row = blockIdx.x * 4 + (threadIdx.x >> 6);  // 0..8191
  const int lane = threadIdx.x & 63;
  const int* p = smask + (size_t)row * S_LEN;
  unsigned long long mine = 0;
#pragma unroll
  for (int r = 0; r < 16; ++r) {
    int m = p[r * 64 + lane];
    unsigned long long w = __ballot(m != 0);
    if (lane == r) mine = w;
  }
  if (lane < 16) mb[(size_t)row * 16 + lane] = mine;
}

// ---------------------------------------------------------------------------
// bf16 MFMA GEMM: C[M,512] = A[M,512] @ Wt^T + bias (+R)
// A bf16 row-major, Wt bf16 [n][k] (pre-transposed). Block = 4 waves,
// wave tile 32m x 64n (2x4 accs), block tile 128m x 64n. Grid (M/128, 8).
// out_mode 0: fp32 [M,512] + residual R ; 1: bf16 [M,512]
// Frag pattern (HW-verified): arg0 = A rows (lane&15=m, k=quad*8+j),
// arg1 = B^T rows (lane&15=n), D: col=lane&15, row=quad*4+reg.
// ---------------------------------------------------------------------------
__global__ __launch_bounds__(256) void gemm_mfma_kern(
    const ushort* __restrict__ A, const ushort* __restrict__ Wt,
    const float* __restrict__ bias, const float* __restrict__ R,
    void* __restrict__ Cout, int out_mode)
{
  const int t = threadIdx.x;
  const int w = t >> 6;
  const int lane = t & 63;
  const int quad = lane >> 4;
  const int i16 = lane & 15;
  const int mbase = blockIdx.x * 128 + w * 32;
  const int nbase = blockIdx.y * 64;

  floatx4 acc[2][4];
#pragma unroll
  for (int mi = 0; mi < 2; ++mi)
#pragma unroll
    for (int ni = 0; ni < 4; ++ni) acc[mi][ni] = (floatx4)(0.f);

  const ushort* Ap = A + (size_t)(mbase + i16) * 512 + quad * 8;
  const ushort* Bp = Wt + (size_t)(nbase + i16) * 512 + quad * 8;

#pragma unroll 4
  for (int k0 = 0; k0 < 512; k0 += 32) {
    short8 af[2], bf[4];
    af[0] = *(const short8*)(Ap + k0);
    af[1] = *(const short8*)(Ap + 16 * 512 + k0);
#pragma unroll
    for (int ni = 0; ni < 4; ++ni)
      bf[ni] = *(const short8*)(Bp + (size_t)ni * 16 * 512 + k0);
#pragma unroll
    for (int mi = 0; mi < 2; ++mi)
#pragma unroll
      for (int ni = 0; ni < 4; ++ni)
        acc[mi][ni] = __builtin_amdgcn_mfma_f32_16x16x32_bf16(af[mi], bf[ni], acc[mi][ni], 0, 0, 0);
  }

  float bv4[4];
#pragma unroll
  for (int ni = 0; ni < 4; ++ni) bv4[ni] = bias[nbase + ni * 16 + i16];

#pragma unroll
  for (int mi = 0; mi < 2; ++mi)
#pragma unroll
    for (int ni = 0; ni < 4; ++ni)
#pragma unroll
      for (int r = 0; r < 4; ++r) {
        const int m = mbase + mi * 16 + quad * 4 + r;
        const int n = nbase + ni * 16 + i16;
        float v = acc[mi][ni][r] + bv4[ni];
        if (out_mode == 0) {
          v += R[(size_t)m * 512 + n];
          ((float*)Cout)[(size_t)m * 512 + n] = v;
        } else {
          ((ushort*)Cout)[(size_t)m * 512 + n] = f2bf(v);
        }
      }
}

// ---------------------------------------------------------------------------
// Transpose V bf16 row-major [B,S,512] -> Vt [B,H,64,S] bf16
// ---------------------------------------------------------------------------
__global__ __launch_bounds__(256) void vtrans_kern(
    const ushort* __restrict__ V, ushort* __restrict__ Vt)
{
  __shared__ __align__(16) ushort tile[64][72];
  const int t = threadIdx.x;
  const int bh = blockIdx.y;
  const int b = bh >> 3;
  const int h = bh & 7;
  const int s0 = blockIdx.x * 64;
  {
    const int r = t >> 2, c0 = (t & 3) * 16;
    const ushort* p = V + ((size_t)b * S_LEN + s0 + r) * D_MOD + h * DK + c0;
    *(short8*)&tile[r][c0] = *(const short8*)p;
    *(short8*)&tile[r][c0 + 8] = *(const short8*)(p + 8);
  }
  __syncthreads();
  {
    const int c = t >> 2, sg = (t & 3) * 16;
    U8 lo, hi;
#pragma unroll
    for (int j = 0; j < 8; ++j) lo.u[j] = tile[sg + j][c];
#pragma unroll
    for (int j = 0; j < 8; ++j) hi.u[j] = tile[sg + 8 + j][c];
    ushort* q = Vt + ((size_t)bh * DK + c) * S_LEN + s0 + sg;
    *(short8*)q = lo.v;
    *(short8*)(q + 8) = hi.v;
  }
}

// ---------------------------------------------------------------------------
// MFMA fused dual-score causal attention, fixed-max softmax (scores bounded
// well below fp32 exp overflow), per-lane l accumulation (no cross-lane ops
// in the k-loop). Block = 4 waves; wave owns 16 q rows. Work-balanced:
// blockIdx.x = p handles q-tiles p and 15-p sequentially (17 k-iters total).
// ---------------------------------------------------------------------------
__global__ __launch_bounds__(256) void attn_mfma_kern(
    const ushort* __restrict__ Qb, const ushort* __restrict__ Kb,
    const ushort* __restrict__ Vt, const ushort* __restrict__ qraw,
    const ushort* __restrict__ kraw,
    const unsigned long long* __restrict__ mbits,
    const float* __restrict__ gammas, ushort* __restrict__ Obf)
{
  __shared__ __align__(16) ushort Plds[4][16][72];

  const int t = threadIdx.x;
  const int w = t >> 6;
  const int lane = t & 63;
  const int quad = lane >> 4;
  const int i16 = lane & 15;
  const int bh = blockIdx.y;
  const int b = bh >> 3;
  const int h = bh & 7;
  const int pr = blockIdx.x;  // 0..7

  const float gam = gammas[h];
  float te = __expf(-log1pf(__expf(gam)));
  te = fminf(fmaxf(te, 1e-5f), 1e5f);
  const float sscale = te * 0.044194173824159216f;  // te / sqrt(512)

  for (int seg = 0; seg < 2; ++seg) {
    const int tile = seg ? (15 - pr) : pr;
    const int qbase = tile * 64 + w * 16;

    // Q fragments (proj + raw), held across the k-loop
    short8 Qp[2], Qr[2];
    {
      const ushort* qp = Qb + ((size_t)b * S_LEN + qbase + i16) * D_MOD + h * DK + quad * 8;
      const ushort* qq = qraw + ((size_t)b * S_LEN + qbase + i16) * D_MOD + h * DK + quad * 8;
#pragma unroll
      for (int s = 0; s < 2; ++s) {
        Qp[s] = *(const short8*)(qp + s * 32);
        Qr[s] = *(const short8*)(qq + s * 32);
      }
    }

    floatx4 Oacc[4];
#pragma unroll
    for (int t4 = 0; t4 < 4; ++t4) Oacc[t4] = (floatx4)(0.f);
    float l_run[4] = {0.f, 0.f, 0.f, 0.f};

    const int kend = qbase + 15;
    for (int k0 = 0; k0 < kend; k0 += 64) {
      // mask bit-words for my 4 rows (16 lanes broadcast each)
      unsigned long long mw[4];
#pragma unroll
      for (int r = 0; r < 4; ++r)
        mw[r] = mbits[((size_t)b * S_LEN + qbase + quad * 4 + r) * 16 + (k0 >> 6)];

      // scores: 16 MFMAs
      floatx4 accp[4], accr[4];
#pragma unroll
      for (int t4 = 0; t4 < 4; ++t4) { accp[t4] = (floatx4)(0.f); accr[t4] = (floatx4)(0.f); }
#pragma unroll
      for (int s = 0; s < 2; ++s) {
        const ushort* kpb = Kb + ((size_t)b * S_LEN + k0 + i16) * D_MOD + h * DK + s * 32 + quad * 8;
        const ushort* krb = kraw + ((size_t)b * S_LEN + k0 + i16) * D_MOD + h * DK + s * 32 + quad * 8;
        short8 kp[4], kr8[4];
#pragma unroll
        for (int t4 = 0; t4 < 4; ++t4) kp[t4] = *(const short8*)(kpb + (size_t)t4 * 16 * D_MOD);
#pragma unroll
        for (int t4 = 0; t4 < 4; ++t4) kr8[t4] = *(const short8*)(krb + (size_t)t4 * 16 * D_MOD);
#pragma unroll
        for (int t4 = 0; t4 < 4; ++t4)
          accp[t4] = __builtin_amdgcn_mfma_f32_16x16x32_bf16(Qp[s], kp[t4], accp[t4], 0, 0, 0);
#pragma unroll
        for (int t4 = 0; t4 < 4; ++t4)
          accr[t4] = __builtin_amdgcn_mfma_f32_16x16x32_bf16(Qr[s], kr8[t4], accr[t4], 0, 0, 0);
      }

      // combine + exp (no max tracking), P -> LDS bf16
#pragma unroll
      for (int r = 0; r < 4; ++r) {
        const int qg = qbase + quad * 4 + r;
#pragma unroll
        for (int t4 = 0; t4 < 4; ++t4) {
          const int kg = k0 + t4 * 16 + i16;
          const float bitf = ((mw[r] >> (t4 * 16 + i16)) & 1ULL) ? sscale : 0.f;
          const float sv = accp[t4][r] * 0.125f + accr[t4][r] * bitf;
          const float p = (kg < qg) ? __expf(sv) : 0.f;
          l_run[r] += p;
          Plds[w][quad * 4 + r][t4 * 16 + i16] = f2bf(p);
        }
      }

      // PV: 8 MFMAs (A = P from LDS, B^T = Vt rows)
#pragma unroll
      for (int s = 0; s < 2; ++s) {
        short8 a = *(const short8*)&Plds[w][i16][s * 32 + quad * 8];
        const ushort* vb = Vt + ((size_t)bh * DK + i16) * S_LEN + k0 + s * 32 + quad * 8;
#pragma unroll
        for (int t4 = 0; t4 < 4; ++t4) {
          short8 bfv = *(const short8*)(vb + (size_t)t4 * 16 * S_LEN);
          Oacc[t4] = __builtin_amdgcn_mfma_f32_16x16x32_bf16(a, bfv, Oacc[t4], 0, 0, 0);
        }
      }
    }

    // epilogue: reduce l across 16 lanes (once), normalize, write O bf16
#pragma unroll
    for (int r = 0; r < 4; ++r) {
      float l = l_run[r];
#pragma unroll
      for (int off = 1; off < 16; off <<= 1) l += __shfl_xor(l, off);
      const float inv = (l > 0.f) ? 1.f / l : 0.f;
      ushort* orow = Obf + ((size_t)b * S_LEN + qbase + quad * 4 + r) * D_MOD + h * DK;
#pragma unroll
      for (int t4 = 0; t4 < 4; ++t4)
        orow[t4 * 16 + i16] = f2bf(Oacc[t4][r] * inv);
    }
  }
}

// ---------------------------------------------------------------------------
// LayerNorm over D=512, one wave per row.
// ---------------------------------------------------------------------------
__global__ __launch_bounds__(256) void ln_kern(
    const float* __restrict__ X, const float* __restrict__ gw,
    const float* __restrict__ bw, float* __restrict__ out)
{
  const int row = blockIdx.x * 4 + (threadIdx.x >> 6);
  const int lane = threadIdx.x & 63;
  const int c = lane * 8;
  const float* xp = &X[(size_t)row * D_MOD + c];
  const float4 x0 = *(const float4*)xp;
  const float4 x1 = *(const float4*)(xp + 4);
  float xv[8] = {x0.x, x0.y, x0.z, x0.w, x1.x, x1.y, x1.z, x1.w};
  float sum = 0.f;
#pragma unroll
  for (int u = 0; u < 8; ++u) sum += xv[u];
#pragma unroll
  for (int off = 1; off < 64; off <<= 1) sum += __shfl_xor(sum, off, 64);
  const float mu = sum * (1.f / 512.f);
  float ss = 0.f;
#pragma unroll
  for (int u = 0; u < 8; ++u) { xv[u] -= mu; ss += xv[u] * xv[u]; }
#pragma unroll
  for (int off = 1; off < 64; off <<= 1) ss += __shfl_xor(ss, off, 64);
  const float rstd = rsqrtf(ss * (1.f / 512.f) + 1e-5f);
  const float4 g0 = *(const float4*)&gw[c];
  const float4 g1 = *(const float4*)&gw[c + 4];
  const float4 b0 = *(const float4*)&bw[c];
  const float4 b1 = *(const float4*)&bw[c + 4];
  float* op = &out[(size_t)row * D_MOD + c];
  *(float4*)op = make_float4(xv[0] * rstd * g0.x + b0.x,
                             xv[1] * rstd * g0.y + b0.y,
                             xv[2] * rstd * g0.z + b0.z,
                             xv[3] * rstd * g0.w + b0.w);
  *(float4*)(op + 4) = make_float4(xv[4] * rstd * g1.x + b1.x,
                                   xv[5] * rstd * g1.y + b1.y,
                                   xv[6] * rstd * g1.z + b1.z,
                                   xv[7] * rstd * g1.w + b1.w);
}

// ---------------------------------------------------------------------------
extern "C" void kernel_launch(void* const* d_in, const int* in_sizes, int n_in,
                              void* d_out, int out_size, void* d_ws, size_t ws_size,
                              hipStream_t stream)
{
  const float* q_in  = (const float*)d_in[0];
  const float* k_in  = (const float*)d_in[1];
  const float* v_in  = (const float*)d_in[2];
  const int*   smask = (const int*)d_in[3];
  const float* Wq = (const float*)d_in[4];
  const float* bq = (const float*)d_in[5];
  const float* Wv = (const float*)d_in[6];
  const float* bv = (const float*)d_in[7];
  const float* Wo = (const float*)d_in[8];
  const float* bo = (const float*)d_in[9];
  const float* gammas = (const float*)d_in[10];
  const float* ln_g = (const float*)d_in[11];
  const float* ln_b = (const float*)d_in[12];
  float* out = (float*)d_out;

  char* ws = (char*)d_ws;
  const size_t BF = (size_t)NB * S_LEN * D_MOD * sizeof(ushort);  // 8 MiB
  ushort* qr  = (ushort*)(ws);                 // [0,8M) ; X fp32 later spans [0,16M)
  ushort* kr  = (ushort*)(ws + BF);            // [8M,16M)
  ushort* vr  = (ushort*)(ws + 2 * BF);        // [16M,24M) ; Vt overlays after V-GEMM
  ushort* Vt  = (ushort*)(ws + 2 * BF);
  ushort* Qbf = (ushort*)(ws + 3 * BF);        // [24M,32M)
  ushort* Kbf = (ushort*)(ws + 4 * BF);        // [32M,40M)
  ushort* Vbf = (ushort*)(ws + 5 * BF);        // [40M,48M) ; Obf overlays after vtrans
  ushort* Obf = (ushort*)(ws + 5 * BF);
  unsigned long long* mbits = (unsigned long long*)(ws + 6 * BF);      // 1 MiB
  ushort* Wqt = (ushort*)(ws + 6 * BF + (1 << 20));                    // 512 KiB
  ushort* Wvt = Wqt + 512 * 512;
  ushort* Wot = Wvt + 512 * 512;
  float*  X   = (float*)ws;                    // [0,16M) overlays qr+kr (dead)

  const dim3 tb(256);
  const int n8 = NB * S_LEN * D_MOD / 8;       // 524288

  cvt_bf16_kern<<<dim3(n8 / 256), tb, 0, stream>>>(q_in, qr, n8);
  cvt_bf16_kern<<<dim3(n8 / 256), tb, 0, stream>>>(k_in, kr, n8);
  cvt_bf16_kern<<<dim3(n8 / 256), tb, 0, stream>>>(v_in, vr, n8);
  wtrans_kern<<<dim3(8, 8), tb, 0, stream>>>(Wq, Wqt);
  wtrans_kern<<<dim3(8, 8), tb, 0, stream>>>(Wv, Wvt);
  wtrans_kern<<<dim3(8, 8), tb, 0, stream>>>(Wo, Wot);
  maskbits_kern<<<dim3(2048), tb, 0, stream>>>(smask, mbits);

  const dim3 gg(64, 8);  // M/128 x N/64
  gemm_mfma_kern<<<gg, tb, 0, stream>>>(qr, Wqt, bq, nullptr, Qbf, 1);
  gemm_mfma_kern<<<gg, tb, 0, stream>>>(kr, Wqt, bq, nullptr, Kbf, 1);
  gemm_mfma_kern<<<gg, tb, 0, stream>>>(vr, Wvt, bv, nullptr, Vbf, 1);

  vtrans_kern<<<dim3(16, 64), tb, 0, stream>>>(Vbf, Vt);

  attn_mfma_kern<<<dim3(8, 64), tb, 0, stream>>>(Qbf, Kbf, Vt, qr, kr, mbits,
                                                 gammas, Obf);

  gemm_mfma_kern<<<gg, tb, 0, stream>>>(Obf, Wot, bo, q_in, X, 0);
  ln_kern<<<2048, tb, 0, stream>>>(X, ln_g, ln_b, out);
}